// Round 3
// baseline (1157.267 us; speedup 1.0000x reference)
//
#include <hip/hip_runtime.h>

// MultiGNN: B=256, A=64 -> 16384 images of 8x15x15
// convs: 8->16 (15->13), 16->32 (13->11), 32->16 (11->9), 16->32 (9->7)
// flatten 32*7*7=1568 -> MLP 128,128,128 -> GCN over 64 agents, E=128
//
// Conv kernel: 2 images/block, aliased LDS arena (79.9KB -> 2 blocks/CU).
// R3 = R2 with compile-risk reduction: item loops are unroll 1 (R2's full
// unroll cloned the whole conv body 3x for the 704/576-item passes).
// R2 design: (1) per-pass weights staged into LDS (loads issued at pass
// start into regs, ds_write after post-pass barrier) -> no global loads in
// inner loops; (2) grid-stride item decompositions rebalanced so all 4
// waves carry near-equal FMA streams; (3) input staging batched.

#define NIMG 16384

// ---------------- LDS arena layout (floats) --------------------------------
// W    @0     : 4608  (current pass weights, [r][co])
// IN   @4608  : 2 x 2400 (8ch x 15 x stride20)      dead after L0 pass
// L1   @4608  : 2 x 4224 (32ch x 11 x stride12)     overlaps dead IN
// L0   @13056 : 2 x 3328 (16ch x 13 x stride16)     dead after L1 pass
// L2   @13056 : 2 x 1728 (16ch x 9 x stride12)      overlaps dead L0
// L2P  @16512 : 2 x 1728 (ci-split partial)
// L3   @16512 : 2 x 1568 (flat 32x7x7)              overlaps dead L2P
#define ARENA_F 19968
#define OFF_W     0
#define OFF_IN    4608
#define OFF_L1    4608
#define OFF_L0    13056
#define OFF_L2    13056
#define OFF_L2P   16512
#define OFF_L3    16512

// ---------------------------------------------------------------------------
// One-time weight transpose: wt[l][r][co] = cw[l][co][r], r = ci*9+ky*3+kx
// ---------------------------------------------------------------------------
__global__ __launch_bounds__(256) void transpose_w(
    const float* __restrict__ c0, const float* __restrict__ c1,
    const float* __restrict__ c2, const float* __restrict__ c3,
    float* __restrict__ w0, float* __restrict__ w1,
    float* __restrict__ w2, float* __restrict__ w3)
{
    int g = blockIdx.x * 256 + threadIdx.x;
    const float* src; float* dst; int CI9, CO, loc;
    if (g < 1152)       { src = c0; dst = w0; CI9 = 72;  CO = 16; loc = g; }
    else if (g < 5760)  { src = c1; dst = w1; CI9 = 144; CO = 32; loc = g - 1152; }
    else if (g < 10368) { src = c2; dst = w2; CI9 = 288; CO = 16; loc = g - 5760; }
    else if (g < 14976) { src = c3; dst = w3; CI9 = 144; CO = 32; loc = g - 10368; }
    else return;
    int r = loc / CO, co = loc - r * CO;
    dst[loc] = src[co * CI9 + r];
}

// ---------------------------------------------------------------------------
// Generic conv pass, grid-stride over items.
// item -> (cog, seg, half, y, img); each item computes SLOTS output columns
// (starting at x0=seg*X0STEP) for COW consecutive output channels, one row.
// Weights read from LDS (sW, [r][co] layout, broadcast-friendly).
// NSPLIT==2: half0 -> sOut0 (+bias, no relu), half1 -> sOutP (raw); a later
// combine pass adds + relus. NSPLIT==1: bias + relu at write.
// RD64: input row window read as NRD float2 (for 8B-aligned odd x0 starts);
// else NRD float4.
// ---------------------------------------------------------------------------
template<int CI, int COW, int NCOG, int HO, int WO, int SLOTS, int NSEG,
         int X0STEP, int NSPLIT,
         int IN_RS, int IN_PLANE, int IN_IMG,
         int OUT_RS, int OUT_PLANE, int OUT_IMG, int NRD, int RD64>
__device__ __forceinline__ void conv_pass(
    const float* __restrict__ sIn, float* __restrict__ sOut0,
    float* __restrict__ sOutP, const float* __restrict__ sW,
    const float* __restrict__ bias, int tid)
{
    constexpr int CO = NCOG * COW;
    constexpr int NITEMS = NCOG * NSEG * NSPLIT * HO * 2;
    constexpr int XN = RD64 ? NRD * 2 : NRD * 4;

#pragma unroll 1
    for (int base = 0; base < NITEMS; base += 256) {
        int item = base + tid;
        if (item < NITEMS) {
            int it = item;
            const int cog  = it % NCOG;   it /= NCOG;
            const int seg  = it % NSEG;   it /= NSEG;
            const int half = it % NSPLIT; it /= NSPLIT;
            const int y    = it % HO;
            const int img  = it / HO;
            const int x0   = seg * X0STEP;
            const int ci0  = half * CI;

            float* __restrict__ sOut = (half == 0) ? sOut0 : sOutP;

            float bw[COW];
#pragma unroll
            for (int c = 0; c < COW; c++) bw[c] = bias[cog * COW + c];

            float acc[SLOTS][COW];
#pragma unroll
            for (int q = 0; q < SLOTS; q++)
#pragma unroll
                for (int c = 0; c < COW; c++) acc[q][c] = 0.0f;

            const float* __restrict__ ip0 = sIn + img * IN_IMG + y * IN_RS + x0;
            const float* __restrict__ wp0 = sW + cog * COW;

#pragma unroll 2
            for (int ci = 0; ci < CI; ci++) {
                const float* __restrict__ ip = ip0 + (ci0 + ci) * IN_PLANE;
                const float* __restrict__ wp = wp0 + (ci0 + ci) * 9 * CO;
#pragma unroll
                for (int ky = 0; ky < 3; ky++) {
                    float xs[XN];
                    const float* __restrict__ rp = ip + ky * IN_RS;
                    if (RD64) {
#pragma unroll
                        for (int j = 0; j < NRD; j++) {
                            float2 v = *(const float2*)(rp + j * 2);
                            xs[j * 2] = v.x; xs[j * 2 + 1] = v.y;
                        }
                    } else {
#pragma unroll
                        for (int j = 0; j < NRD; j++) {
                            float4 v = *(const float4*)(rp + j * 4);
                            xs[j * 4] = v.x; xs[j * 4 + 1] = v.y;
                            xs[j * 4 + 2] = v.z; xs[j * 4 + 3] = v.w;
                        }
                    }
                    float w[3][COW];
#pragma unroll
                    for (int kx = 0; kx < 3; kx++) {
                        if (COW == 2) {
                            float2 t = *(const float2*)(wp + (ky * 3 + kx) * CO);
                            w[kx][0] = t.x; w[kx][1] = t.y;
                        } else {
                            w[kx][0] = wp[(ky * 3 + kx) * CO];
                        }
                    }
#pragma unroll
                    for (int kx = 0; kx < 3; kx++)
#pragma unroll
                        for (int q = 0; q < SLOTS; q++) {
                            const float iv = xs[q + kx];
#pragma unroll
                            for (int c = 0; c < COW; c++)
                                acc[q][c] += iv * w[kx][c];
                        }
                }
            }

            float* __restrict__ op = sOut + img * OUT_IMG + y * OUT_RS;
#pragma unroll
            for (int q = 0; q < SLOTS; q++) {
                if (x0 + q < WO) {
#pragma unroll
                    for (int c = 0; c < COW; c++) {
                        float v = acc[q][c];
                        if (NSPLIT == 1)      v = fmaxf(v + bw[c], 0.0f);
                        else if (half == 0)   v = v + bw[c];
                        op[(cog * COW + c) * OUT_PLANE + x0 + q] = v;
                    }
                }
            }
        }
    }
}

__global__ __launch_bounds__(256, 2) void conv_stack3(
    const float* __restrict__ states,
    const float* __restrict__ wt0, const float* __restrict__ cb0,
    const float* __restrict__ wt1, const float* __restrict__ cb1,
    const float* __restrict__ wt2, const float* __restrict__ cb2,
    const float* __restrict__ wt3, const float* __restrict__ cb3,
    float* __restrict__ x0out)
{
    __shared__ float A[ARENA_F];
    const int tid = threadIdx.x;
    float4 wreg[5];

#define WSTAGE_LOAD(src, n4)                                              \
    { _Pragma("unroll") for (int j = 0; j < 5; j++) {                     \
          int i = tid + j * 256;                                          \
          if (i < (n4)) wreg[j] = *(const float4*)((src) + i * 4); } }
#define WSTAGE_WRITE(n4)                                                  \
    { _Pragma("unroll") for (int j = 0; j < 5; j++) {                     \
          int i = tid + j * 256;                                          \
          if (i < (n4)) *(float4*)(A + OFF_W + i * 4) = wreg[j]; } }

    // ---- stage input (batched: all loads, then all writes) + W0 ----
    const float* gin = states + (size_t)blockIdx.x * 3600;
    {
        float v[15];
#pragma unroll
        for (int j = 0; j < 15; j++) {
            int e = tid + j * 256;
            if (e < 3600) v[j] = gin[e];
        }
#pragma unroll
        for (int j = 0; j < 15; j++) {
            int e = tid + j * 256;
            if (e < 3600) {
                int img = e / 1800, r = e - img * 1800;
                int ci = r / 225;  r -= ci * 225;
                int y = r / 15, x = r - y * 15;
                A[OFF_IN + img * 2400 + ci * 300 + y * 20 + x] = v[j];
            }
        }
        for (int i = tid; i < 288; i += 256)
            *(float4*)(A + OFF_W + i * 4) = *(const float4*)(wt0 + i * 4);
    }
    __syncthreads();

    // L0: 8->16, 15->13. co-pair x full row. 208 items.
    WSTAGE_LOAD(wt1, 1152);
    conv_pass<8, 2, 8, 13, 13, 13, 1, 0, 1, 20, 300, 2400, 16, 208, 3328, 4, 0>(
        A + OFF_IN, A + OFF_L0, A + OFF_L0, A + OFF_W, cb0, tid);
    __syncthreads();
    WSTAGE_WRITE(1152);
    __syncthreads();

    // L1: 16->32, 13->11. co-pair x half-row (S=6, x0 in {0,6}). 704 items.
    WSTAGE_LOAD(wt2, 1152);
    conv_pass<16, 2, 16, 11, 11, 6, 2, 6, 1, 16, 208, 3328, 12, 132, 4224, 4, 1>(
        A + OFF_L0, A + OFF_L1, A + OFF_L1, A + OFF_W, cb1, tid);
    __syncthreads();
    WSTAGE_WRITE(1152);
    __syncthreads();

    // L2: 32->16, 11->9. co-single x full row x ci-split2. 576 items.
    WSTAGE_LOAD(wt3, 1152);
    conv_pass<16, 1, 16, 9, 9, 9, 1, 0, 2, 12, 132, 4224, 12, 108, 1728, 3, 0>(
        A + OFF_L1, A + OFF_L2, A + OFF_L2P, A + OFF_W, cb2, tid);
    __syncthreads();
    WSTAGE_WRITE(1152);
    // combine ci-split halves + relu (in place, disjoint from W buffer)
    for (int i = tid; i < 3456; i += 256) {
        float s = A[OFF_L2 + i] + A[OFF_L2P + i];
        A[OFF_L2 + i] = fmaxf(s, 0.0f);
    }
    __syncthreads();

    // L3: 16->32, 9->7. co-pair x full row, flat out. 224 items.
    conv_pass<16, 2, 16, 7, 7, 7, 1, 0, 1, 12, 108, 1728, 7, 49, 1568, 3, 0>(
        A + OFF_L2, A + OFF_L3, A + OFF_L3, A + OFF_W, cb3, tid);
    __syncthreads();

    // coalesced global store (relu already applied in-pass)
    float* gout = x0out + (size_t)blockIdx.x * 3136;
    for (int i = tid; i < 784; i += 256)
        *(float4*)(gout + i * 4) = *(const float4*)(A + OFF_L3 + i * 4);

#undef WSTAGE_LOAD
#undef WSTAGE_WRITE
}

// ---------------------------------------------------------------------------
// GEMM: C[M x 128] = A[M x K] @ W[K x 128] (+bias)(+relu); M-tile 64
// ---------------------------------------------------------------------------
template<int K, bool RELU>
__global__ __launch_bounds__(256) void gemm128(
    const float* __restrict__ Am, const float* __restrict__ Wm,
    const float* __restrict__ bias, float* __restrict__ Cm)
{
    __shared__ float As[64 * 36];
    __shared__ float Ws[32 * 128];

    const int tid = threadIdx.x;
    const int m0  = blockIdx.x * 64;
    const int rg  = tid >> 4;
    const int cg  = tid & 15;

    float acc[4][8];
#pragma unroll
    for (int r = 0; r < 4; r++)
#pragma unroll
        for (int c = 0; c < 8; c++) acc[r][c] = 0.0f;

    for (int k0 = 0; k0 < K; k0 += 32) {
        __syncthreads();
#pragma unroll
        for (int it = 0; it < 2; it++) {
            int idx = tid + it * 256;
            int row = idx >> 3;
            int c4  = idx & 7;
            float4 v = *(const float4*)(Am + (size_t)(m0 + row) * K + k0 + c4 * 4);
            *(float4*)(As + row * 36 + c4 * 4) = v;
        }
#pragma unroll
        for (int it = 0; it < 4; it++) {
            int idx = tid + it * 256;
            int kr  = idx >> 5;
            int c4  = idx & 31;
            float4 v = *(const float4*)(Wm + (size_t)(k0 + kr) * 128 + c4 * 4);
            *(float4*)(Ws + kr * 128 + c4 * 4) = v;
        }
        __syncthreads();

#pragma unroll
        for (int kk = 0; kk < 32; kk++) {
            float a0 = As[(rg * 4 + 0) * 36 + kk];
            float a1 = As[(rg * 4 + 1) * 36 + kk];
            float a2 = As[(rg * 4 + 2) * 36 + kk];
            float a3 = As[(rg * 4 + 3) * 36 + kk];
            float4 w0 = *(const float4*)(Ws + kk * 128 + cg * 8);
            float4 w1 = *(const float4*)(Ws + kk * 128 + cg * 8 + 4);
            acc[0][0] += a0 * w0.x; acc[0][1] += a0 * w0.y; acc[0][2] += a0 * w0.z; acc[0][3] += a0 * w0.w;
            acc[0][4] += a0 * w1.x; acc[0][5] += a0 * w1.y; acc[0][6] += a0 * w1.z; acc[0][7] += a0 * w1.w;
            acc[1][0] += a1 * w0.x; acc[1][1] += a1 * w0.y; acc[1][2] += a1 * w0.z; acc[1][3] += a1 * w0.w;
            acc[1][4] += a1 * w1.x; acc[1][5] += a1 * w1.y; acc[1][6] += a1 * w1.z; acc[1][7] += a1 * w1.w;
            acc[2][0] += a2 * w0.x; acc[2][1] += a2 * w0.y; acc[2][2] += a2 * w0.z; acc[2][3] += a2 * w0.w;
            acc[2][4] += a2 * w1.x; acc[2][5] += a2 * w1.y; acc[2][6] += a2 * w1.z; acc[2][7] += a2 * w1.w;
            acc[3][0] += a3 * w0.x; acc[3][1] += a3 * w0.y; acc[3][2] += a3 * w0.z; acc[3][3] += a3 * w0.w;
            acc[3][4] += a3 * w1.x; acc[3][5] += a3 * w1.y; acc[3][6] += a3 * w1.z; acc[3][7] += a3 * w1.w;
        }
    }

#pragma unroll
    for (int r = 0; r < 4; r++) {
        int row = m0 + rg * 4 + r;
        float v[8];
#pragma unroll
        for (int c = 0; c < 8; c++) {
            float x = acc[r][c];
            if (bias) x += bias[cg * 8 + c];
            if (RELU) x = fmaxf(x, 0.0f);
            v[c] = x;
        }
        float* gp = Cm + (size_t)row * 128 + cg * 8;
        *(float4*)(gp)     = make_float4(v[0], v[1], v[2], v[3]);
        *(float4*)(gp + 4) = make_float4(v[4], v[5], v[6], v[7]);
    }
}

// ---------------------------------------------------------------------------
// GCN aggregation: out[b,j] = dinv_j * sum_i (adj[b,i,j]*dinv_i*xw[b,i]) + gb
// ---------------------------------------------------------------------------
__global__ __launch_bounds__(256) void gcn_agg(
    const float* __restrict__ adj, const float* __restrict__ xw,
    const float* __restrict__ gb, float* __restrict__ outp)
{
    __shared__ float sAdj[64 * 64];
    __shared__ float sXW[64 * 128];
    __shared__ float sDinv[64];

    const int b = blockIdx.x;
    const int tid = threadIdx.x;

    const float* ga = adj + (size_t)b * 4096;
#pragma unroll
    for (int it = 0; it < 4; it++) {
        int idx = tid + it * 256;
        *(float4*)(sAdj + idx * 4) = *(const float4*)(ga + idx * 4);
    }
    const float* gx = xw + (size_t)b * 8192;
#pragma unroll
    for (int it = 0; it < 8; it++) {
        int idx = tid + it * 256;
        *(float4*)(sXW + idx * 4) = *(const float4*)(gx + idx * 4);
    }
    __syncthreads();

    if (tid < 64) {
        float d = 0.0f;
        for (int i = 0; i < 64; i++) d += sAdj[i * 64 + tid];
        sDinv[tid] = (d > 0.0f) ? rsqrtf(d) : 0.0f;
    }
    __syncthreads();

#pragma unroll
    for (int it = 0; it < 8; it++) {
        int idx = tid + it * 256;
        int i = idx >> 5;
        float s = sDinv[i];
        float4 v = *(float4*)(sXW + idx * 4);
        v.x *= s; v.y *= s; v.z *= s; v.w *= s;
        *(float4*)(sXW + idx * 4) = v;
    }
    __syncthreads();

    const int j  = tid >> 2;
    const int eb = (tid & 3) * 32;
    float acc[32];
#pragma unroll
    for (int e = 0; e < 32; e++) acc[e] = 0.0f;

    for (int i = 0; i < 64; i++) {
        float wgt = sAdj[i * 64 + j];
        const float* xp = sXW + i * 128 + eb;
#pragma unroll
        for (int e4 = 0; e4 < 8; e4++) {
            float4 v = *(const float4*)(xp + e4 * 4);
            acc[e4 * 4 + 0] += wgt * v.x;
            acc[e4 * 4 + 1] += wgt * v.y;
            acc[e4 * 4 + 2] += wgt * v.z;
            acc[e4 * 4 + 3] += wgt * v.w;
        }
    }

    const float dj = sDinv[j];
    float* go = outp + ((size_t)b * 64 + j) * 128 + eb;
#pragma unroll
    for (int e4 = 0; e4 < 8; e4++) {
        float4 v;
        v.x = acc[e4 * 4 + 0] * dj + gb[eb + e4 * 4 + 0];
        v.y = acc[e4 * 4 + 1] * dj + gb[eb + e4 * 4 + 1];
        v.z = acc[e4 * 4 + 2] * dj + gb[eb + e4 * 4 + 2];
        v.w = acc[e4 * 4 + 3] * dj + gb[eb + e4 * 4 + 3];
        *(float4*)(go + e4 * 4) = v;
    }
}

// ---------------------------------------------------------------------------
extern "C" void kernel_launch(void* const* d_in, const int* in_sizes, int n_in,
                              void* d_out, int out_size, void* d_ws, size_t ws_size,
                              hipStream_t stream)
{
    const float* states = (const float*)d_in[0];
    const float* adj    = (const float*)d_in[1];
    const float* cw0 = (const float*)d_in[2];  const float* cb0 = (const float*)d_in[3];
    const float* cw1 = (const float*)d_in[4];  const float* cb1 = (const float*)d_in[5];
    const float* cw2 = (const float*)d_in[6];  const float* cb2 = (const float*)d_in[7];
    const float* cw3 = (const float*)d_in[8];  const float* cb3 = (const float*)d_in[9];
    const float* mw0 = (const float*)d_in[10]; const float* mb0 = (const float*)d_in[11];
    const float* mw1 = (const float*)d_in[12]; const float* mb1 = (const float*)d_in[13];
    const float* mw2 = (const float*)d_in[14]; const float* mb2 = (const float*)d_in[15];
    const float* gw  = (const float*)d_in[16]; const float* gb  = (const float*)d_in[17];

    float* ws = (float*)d_ws;
    float* X0 = ws;                                   // 16384*1568 floats
    float* Bu = ws + (size_t)25690112;                // 16384*128
    float* Cu = Bu + (size_t)2097152;                 // 16384*128
    float* WT0 = Cu + (size_t)2097152;                // 1152
    float* WT1 = WT0 + 1152;                          // 4608
    float* WT2 = WT1 + 4608;                          // 4608
    float* WT3 = WT2 + 4608;                          // 4608

    float* out = (float*)d_out;

    transpose_w<<<59, 256, 0, stream>>>(cw0, cw1, cw2, cw3, WT0, WT1, WT2, WT3);
    conv_stack3<<<NIMG / 2, 256, 0, stream>>>(states, WT0, cb0, WT1, cb1,
                                              WT2, cb2, WT3, cb3, X0);
    gemm128<1568, true ><<<256, 256, 0, stream>>>(X0, mw0, mb0, Bu);   // H1
    gemm128<128,  true ><<<256, 256, 0, stream>>>(Bu, mw1, mb1, Cu);   // H2
    gemm128<128,  false><<<256, 256, 0, stream>>>(Cu, mw2, mb2, Bu);   // feats
    gemm128<128,  false><<<256, 256, 0, stream>>>(Bu, gw, nullptr, Cu);// xw
    gcn_agg<<<256, 256, 0, stream>>>(adj, Cu, gb, out);
}

// Round 4
// 1036.961 us; speedup vs baseline: 1.1160x; 1.1160x over previous
//
#include <hip/hip_runtime.h>

// MultiGNN: B=256, A=64 -> 16384 images of 8x15x15
// convs: 8->16 (15->13), 16->32 (13->11), 32->16 (11->9), 16->32 (9->7)
// flatten 32*7*7=1568 -> MLP 128,128,128 -> GCN over 64 agents, E=128
//
// R4: occupancy restructure. ONE image per block -> aliased arena peak is
// L0+L1 = 7552 floats = 30.2KB -> 5 blocks/CU (20 waves, 5/SIMD) vs the
// previous 2-image 60-80KB arena (2 blocks/CU, 2 waves/SIMD, VALUBusy
// pinned at 61% with ~39% no-issue cycles). __launch_bounds__(256,5) caps
// VGPR ~100 (items need ~60; ci-loop unroll 1 to avoid R3's spill
// disaster). Weights from global (R3 proved LDS-staging them is a net
// loss); L0 XOR swizzle kept; L2/L3 ci-splits dropped (full-ci items,
// relu fused, no combine passes).

#define NIMG 16384

// ---------------- LDS arena layout (floats, 1 image) -----------------------
// L0 @0    : 3328 (16ch x 13 x stride16, x XOR-swizzled per row)
// IN @3328 : 2400 (8ch x 15 x stride20)      dead after L0 pass
// L1 @3328 : 4224 (32ch x 11 x stride12)     overlaps dead IN
// L2 @0    : 1728 (16ch x 9 x stride12)      overlaps dead L0
// L3 @1728 : 1568 (flat 32x7x7)              after dead L0 tail
// peak coexistence: L0+L1 = 7552 floats = 30208 B -> 5 blocks/CU
#define ARENA_F 7552
#define OFF_L0    0
#define OFF_IN    3328
#define OFF_L1    3328
#define OFF_L2    0
#define OFF_L3    1728

// ---------------------------------------------------------------------------
// One-time weight transpose: wt[l][r][co] = cw[l][co][r], r = ci*9+ky*3+kx
// ---------------------------------------------------------------------------
__global__ __launch_bounds__(256) void transpose_w(
    const float* __restrict__ c0, const float* __restrict__ c1,
    const float* __restrict__ c2, const float* __restrict__ c3,
    float* __restrict__ w0, float* __restrict__ w1,
    float* __restrict__ w2, float* __restrict__ w3)
{
    int g = blockIdx.x * 256 + threadIdx.x;
    const float* src; float* dst; int CI9, CO, loc;
    if (g < 1152)       { src = c0; dst = w0; CI9 = 72;  CO = 16; loc = g; }
    else if (g < 5760)  { src = c1; dst = w1; CI9 = 144; CO = 32; loc = g - 1152; }
    else if (g < 10368) { src = c2; dst = w2; CI9 = 288; CO = 16; loc = g - 5760; }
    else if (g < 14976) { src = c3; dst = w3; CI9 = 144; CO = 32; loc = g - 10368; }
    else return;
    int r = loc / CO, co = loc - r * CO;
    dst[loc] = src[co * CI9 + r];
}

// ---------------------------------------------------------------------------
// Single-image conv pass. item = cog + NCOG*y (<=256, single shot).
// Each item: one output row y, COW consecutive output channels, full row
// (SLOTS == WO columns), full CI reduction. Weights from global ([r][co]).
// IN_SWZ/OUT_SWZ: rows stored with x ^ ((y&3)<<2) (quad-preserving XOR ->
// float4 LDS reads stay x-contiguous; kills stride-16 bank conflicts).
// ---------------------------------------------------------------------------
template<int CI, int COW, int NCOG, int HO, int SLOTS,
         int IN_RS, int IN_PLANE, int OUT_RS, int OUT_PLANE,
         int NRD, int IN_SWZ, int OUT_SWZ>
__device__ __forceinline__ void conv1(
    const float* __restrict__ sIn, float* __restrict__ sOut,
    const float* __restrict__ wt, const float* __restrict__ bias, int tid)
{
    constexpr int CO = NCOG * COW;
    constexpr int NITEMS = NCOG * HO;
    static_assert(NITEMS <= 256, "single shot");
    if (tid >= NITEMS) return;

    const int cog = tid % NCOG;
    const int y   = tid / NCOG;

    float acc[SLOTS][COW];
#pragma unroll
    for (int c = 0; c < COW; c++) {
        const float b = bias[cog * COW + c];
#pragma unroll
        for (int q = 0; q < SLOTS; q++) acc[q][c] = b;
    }

    const float* __restrict__ ip0 = sIn + y * IN_RS;
    const float* __restrict__ wp0 = wt + cog * COW;

#pragma unroll 1
    for (int ci = 0; ci < CI; ci++) {
        const float* __restrict__ ip = ip0 + ci * IN_PLANE;
        const float* __restrict__ wp = wp0 + ci * 9 * CO;
#pragma unroll
        for (int ky = 0; ky < 3; ky++) {
            float xs[NRD * 4];
            const float* __restrict__ rp = ip + ky * IN_RS;
            const int sw = IN_SWZ ? (((y + ky) & 3) << 2) : 0;
#pragma unroll
            for (int j = 0; j < NRD; j++) {
                float4 v = *(const float4*)(rp + ((j * 4) ^ sw));
                xs[j * 4] = v.x; xs[j * 4 + 1] = v.y;
                xs[j * 4 + 2] = v.z; xs[j * 4 + 3] = v.w;
            }
            float w[3][COW];
#pragma unroll
            for (int kx = 0; kx < 3; kx++) {
                if (COW == 2) {
                    float2 t = *(const float2*)(wp + (ky * 3 + kx) * CO);
                    w[kx][0] = t.x; w[kx][1] = t.y;
                } else {
                    w[kx][0] = wp[(ky * 3 + kx) * CO];
                }
            }
#pragma unroll
            for (int kx = 0; kx < 3; kx++)
#pragma unroll
                for (int q = 0; q < SLOTS; q++) {
                    const float iv = xs[q + kx];
#pragma unroll
                    for (int c = 0; c < COW; c++)
                        acc[q][c] += iv * w[kx][c];
                }
        }
    }

    const int swo = OUT_SWZ ? ((y & 3) << 2) : 0;
    float* __restrict__ op = sOut + y * OUT_RS;
#pragma unroll
    for (int q = 0; q < SLOTS; q++)
#pragma unroll
        for (int c = 0; c < COW; c++)
            op[(cog * COW + c) * OUT_PLANE + (q ^ swo)] = fmaxf(acc[q][c], 0.0f);
}

__global__ __launch_bounds__(256, 5) void conv_stack3(
    const float* __restrict__ states,
    const float* __restrict__ wt0, const float* __restrict__ cb0,
    const float* __restrict__ wt1, const float* __restrict__ cb1,
    const float* __restrict__ wt2, const float* __restrict__ cb2,
    const float* __restrict__ wt3, const float* __restrict__ cb3,
    float* __restrict__ x0out)
{
    __shared__ float A[ARENA_F];
    const int tid = threadIdx.x;

    // ---- stage input with row re-pad 15 -> stride 20 ----
    const float* gin = states + (size_t)blockIdx.x * 1800;
#pragma unroll
    for (int j = 0; j < 8; j++) {
        int e = tid + j * 256;
        if (e < 1800) {
            int ci = e / 225, r = e - ci * 225;
            int y = r / 15, x = r - y * 15;
            A[OFF_IN + ci * 300 + y * 20 + x] = gin[e];
        }
    }
    __syncthreads();

    // L0: 8->16, 15->13. co-pair x row = 104 items. out stride16 swizzled.
    conv1<8, 2, 8, 13, 13, 20, 300, 16, 208, 4, 0, 1>(
        A + OFF_IN, A + OFF_L0, wt0, cb0, tid);
    __syncthreads();

    // L1: 16->32, 13->11. co-pair x row = 176 items. in swizzled s16.
    conv1<16, 2, 16, 11, 11, 16, 208, 12, 132, 4, 1, 0>(
        A + OFF_L0, A + OFF_L1, wt1, cb1, tid);
    __syncthreads();

    // L2: 32->16, 11->9. co-single x row = 144 items, full ci.
    conv1<32, 1, 16, 9, 9, 12, 132, 12, 108, 3, 0, 0>(
        A + OFF_L1, A + OFF_L2, wt2, cb2, tid);
    __syncthreads();

    // L3: 16->32, 9->7. co-pair x row = 112 items, flat out (s7/plane49).
    conv1<16, 2, 16, 7, 7, 12, 108, 7, 49, 3, 0, 0>(
        A + OFF_L2, A + OFF_L3, wt3, cb3, tid);
    __syncthreads();

    // coalesced global store (relu already applied in-pass)
    float* gout = x0out + (size_t)blockIdx.x * 1568;
#pragma unroll
    for (int j = 0; j < 2; j++) {
        int i = tid + j * 256;
        if (i < 392)
            *(float4*)(gout + i * 4) = *(const float4*)(A + OFF_L3 + i * 4);
    }
}

// ---------------------------------------------------------------------------
// GEMM: C[M x 128] = A[M x K] @ W[K x 128] (+bias)(+relu); M-tile 64
// ---------------------------------------------------------------------------
template<int K, bool RELU>
__global__ __launch_bounds__(256) void gemm128(
    const float* __restrict__ Am, const float* __restrict__ Wm,
    const float* __restrict__ bias, float* __restrict__ Cm)
{
    __shared__ float As[64 * 36];
    __shared__ float Ws[32 * 128];

    const int tid = threadIdx.x;
    const int m0  = blockIdx.x * 64;
    const int rg  = tid >> 4;
    const int cg  = tid & 15;

    float acc[4][8];
#pragma unroll
    for (int r = 0; r < 4; r++)
#pragma unroll
        for (int c = 0; c < 8; c++) acc[r][c] = 0.0f;

    for (int k0 = 0; k0 < K; k0 += 32) {
        __syncthreads();
#pragma unroll
        for (int it = 0; it < 2; it++) {
            int idx = tid + it * 256;
            int row = idx >> 3;
            int c4  = idx & 7;
            float4 v = *(const float4*)(Am + (size_t)(m0 + row) * K + k0 + c4 * 4);
            *(float4*)(As + row * 36 + c4 * 4) = v;
        }
#pragma unroll
        for (int it = 0; it < 4; it++) {
            int idx = tid + it * 256;
            int kr  = idx >> 5;
            int c4  = idx & 31;
            float4 v = *(const float4*)(Wm + (size_t)(k0 + kr) * 128 + c4 * 4);
            *(float4*)(Ws + kr * 128 + c4 * 4) = v;
        }
        __syncthreads();

#pragma unroll
        for (int kk = 0; kk < 32; kk++) {
            float a0 = As[(rg * 4 + 0) * 36 + kk];
            float a1 = As[(rg * 4 + 1) * 36 + kk];
            float a2 = As[(rg * 4 + 2) * 36 + kk];
            float a3 = As[(rg * 4 + 3) * 36 + kk];
            float4 w0 = *(const float4*)(Ws + kk * 128 + cg * 8);
            float4 w1 = *(const float4*)(Ws + kk * 128 + cg * 8 + 4);
            acc[0][0] += a0 * w0.x; acc[0][1] += a0 * w0.y; acc[0][2] += a0 * w0.z; acc[0][3] += a0 * w0.w;
            acc[0][4] += a0 * w1.x; acc[0][5] += a0 * w1.y; acc[0][6] += a0 * w1.z; acc[0][7] += a0 * w1.w;
            acc[1][0] += a1 * w0.x; acc[1][1] += a1 * w0.y; acc[1][2] += a1 * w0.z; acc[1][3] += a1 * w0.w;
            acc[1][4] += a1 * w1.x; acc[1][5] += a1 * w1.y; acc[1][6] += a1 * w1.z; acc[1][7] += a1 * w1.w;
            acc[2][0] += a2 * w0.x; acc[2][1] += a2 * w0.y; acc[2][2] += a2 * w0.z; acc[2][3] += a2 * w0.w;
            acc[2][4] += a2 * w1.x; acc[2][5] += a2 * w1.y; acc[2][6] += a2 * w1.z; acc[2][7] += a2 * w1.w;
            acc[3][0] += a3 * w0.x; acc[3][1] += a3 * w0.y; acc[3][2] += a3 * w0.z; acc[3][3] += a3 * w0.w;
            acc[3][4] += a3 * w1.x; acc[3][5] += a3 * w1.y; acc[3][6] += a3 * w1.z; acc[3][7] += a3 * w1.w;
        }
    }

#pragma unroll
    for (int r = 0; r < 4; r++) {
        int row = m0 + rg * 4 + r;
        float v[8];
#pragma unroll
        for (int c = 0; c < 8; c++) {
            float x = acc[r][c];
            if (bias) x += bias[cg * 8 + c];
            if (RELU) x = fmaxf(x, 0.0f);
            v[c] = x;
        }
        float* gp = Cm + (size_t)row * 128 + cg * 8;
        *(float4*)(gp)     = make_float4(v[0], v[1], v[2], v[3]);
        *(float4*)(gp + 4) = make_float4(v[4], v[5], v[6], v[7]);
    }
}

// ---------------------------------------------------------------------------
// GCN aggregation: out[b,j] = dinv_j * sum_i (adj[b,i,j]*dinv_i*xw[b,i]) + gb
// ---------------------------------------------------------------------------
__global__ __launch_bounds__(256) void gcn_agg(
    const float* __restrict__ adj, const float* __restrict__ xw,
    const float* __restrict__ gb, float* __restrict__ outp)
{
    __shared__ float sAdj[64 * 64];
    __shared__ float sXW[64 * 128];
    __shared__ float sDinv[64];

    const int b = blockIdx.x;
    const int tid = threadIdx.x;

    const float* ga = adj + (size_t)b * 4096;
#pragma unroll
    for (int it = 0; it < 4; it++) {
        int idx = tid + it * 256;
        *(float4*)(sAdj + idx * 4) = *(const float4*)(ga + idx * 4);
    }
    const float* gx = xw + (size_t)b * 8192;
#pragma unroll
    for (int it = 0; it < 8; it++) {
        int idx = tid + it * 256;
        *(float4*)(sXW + idx * 4) = *(const float4*)(gx + idx * 4);
    }
    __syncthreads();

    if (tid < 64) {
        float d = 0.0f;
        for (int i = 0; i < 64; i++) d += sAdj[i * 64 + tid];
        sDinv[tid] = (d > 0.0f) ? rsqrtf(d) : 0.0f;
    }
    __syncthreads();

#pragma unroll
    for (int it = 0; it < 8; it++) {
        int idx = tid + it * 256;
        int i = idx >> 5;
        float s = sDinv[i];
        float4 v = *(float4*)(sXW + idx * 4);
        v.x *= s; v.y *= s; v.z *= s; v.w *= s;
        *(float4*)(sXW + idx * 4) = v;
    }
    __syncthreads();

    const int j  = tid >> 2;
    const int eb = (tid & 3) * 32;
    float acc[32];
#pragma unroll
    for (int e = 0; e < 32; e++) acc[e] = 0.0f;

    for (int i = 0; i < 64; i++) {
        float wgt = sAdj[i * 64 + j];
        const float* xp = sXW + i * 128 + eb;
#pragma unroll
        for (int e4 = 0; e4 < 8; e4++) {
            float4 v = *(const float4*)(xp + e4 * 4);
            acc[e4 * 4 + 0] += wgt * v.x;
            acc[e4 * 4 + 1] += wgt * v.y;
            acc[e4 * 4 + 2] += wgt * v.z;
            acc[e4 * 4 + 3] += wgt * v.w;
        }
    }

    const float dj = sDinv[j];
    float* go = outp + ((size_t)b * 64 + j) * 128 + eb;
#pragma unroll
    for (int e4 = 0; e4 < 8; e4++) {
        float4 v;
        v.x = acc[e4 * 4 + 0] * dj + gb[eb + e4 * 4 + 0];
        v.y = acc[e4 * 4 + 1] * dj + gb[eb + e4 * 4 + 1];
        v.z = acc[e4 * 4 + 2] * dj + gb[eb + e4 * 4 + 2];
        v.w = acc[e4 * 4 + 3] * dj + gb[eb + e4 * 4 + 3];
        *(float4*)(go + e4 * 4) = v;
    }
}

// ---------------------------------------------------------------------------
extern "C" void kernel_launch(void* const* d_in, const int* in_sizes, int n_in,
                              void* d_out, int out_size, void* d_ws, size_t ws_size,
                              hipStream_t stream)
{
    const float* states = (const float*)d_in[0];
    const float* adj    = (const float*)d_in[1];
    const float* cw0 = (const float*)d_in[2];  const float* cb0 = (const float*)d_in[3];
    const float* cw1 = (const float*)d_in[4];  const float* cb1 = (const float*)d_in[5];
    const float* cw2 = (const float*)d_in[6];  const float* cb2 = (const float*)d_in[7];
    const float* cw3 = (const float*)d_in[8];  const float* cb3 = (const float*)d_in[9];
    const float* mw0 = (const float*)d_in[10]; const float* mb0 = (const float*)d_in[11];
    const float* mw1 = (const float*)d_in[12]; const float* mb1 = (const float*)d_in[13];
    const float* mw2 = (const float*)d_in[14]; const float* mb2 = (const float*)d_in[15];
    const float* gw  = (const float*)d_in[16]; const float* gb  = (const float*)d_in[17];

    float* ws = (float*)d_ws;
    float* X0 = ws;                                   // 16384*1568 floats
    float* Bu = ws + (size_t)25690112;                // 16384*128
    float* Cu = Bu + (size_t)2097152;                 // 16384*128
    float* WT0 = Cu + (size_t)2097152;                // 1152
    float* WT1 = WT0 + 1152;                          // 4608
    float* WT2 = WT1 + 4608;                          // 4608
    float* WT3 = WT2 + 4608;                          // 4608

    float* out = (float*)d_out;

    transpose_w<<<59, 256, 0, stream>>>(cw0, cw1, cw2, cw3, WT0, WT1, WT2, WT3);
    conv_stack3<<<NIMG, 256, 0, stream>>>(states, WT0, cb0, WT1, cb1,
                                          WT2, cb2, WT3, cb3, X0);
    gemm128<1568, true ><<<256, 256, 0, stream>>>(X0, mw0, mb0, Bu);   // H1
    gemm128<128,  true ><<<256, 256, 0, stream>>>(Bu, mw1, mb1, Cu);   // H2
    gemm128<128,  false><<<256, 256, 0, stream>>>(Cu, mw2, mb2, Bu);   // feats
    gemm128<128,  false><<<256, 256, 0, stream>>>(Bu, gw, nullptr, Cu);// xw
    gcn_agg<<<256, 256, 0, stream>>>(adj, Cu, gb, out);
}